// Round 3
// baseline (583.415 us; speedup 1.0000x reference)
//
#include <hip/hip_runtime.h>
#include <math.h>

#define NN 80
#define MITERS 50
#define NTHREADS 1024

typedef float f32x2 __attribute__((ext_vector_type(2)));

// paired-b interleaved layout for the phase-A operands (x and tgt):
// element [row][k] at block (row>>2)*324 + (k>>1)*8 + (row&3)*2 + (k&1)
#define PIDX(row, k) \
  ((((row) >> 2) * 324) + (((k) >> 1) * 8) + ((((row) & 3)) << 1) + ((k) & 1))

#define MAX3(m, a, b) \
  asm("v_max3_f32 %0, %0, %1, %2" : "+v"(m) : "v"(a), "v"(b))

#define MMSTRIDE 84

// LDS floats: XT 6480 | TT 6480 | SRC 6400 | DL 6400 | MM0 6720 | MM1 6720 |
//             FR/FA/RD/AD 320 | WSUM 32 | LSUM 16   = 39568 floats = 154.6 KiB
#define LDS_FLOATS (6480 + 6480 + 6400 + 6400 + 6720 + 6720 + 320 + 32 + 16)

__global__ void __launch_bounds__(NTHREADS)
grf_kernel(const float* __restrict__ recon, const float* __restrict__ adj,
           float* __restrict__ out) {
  extern __shared__ float lds[];
  float* XT_pp = lds;                  // x state, paired layout
  float* TT_pp = XT_pp + 6480;         // tgt, paired layout
  float* SRC   = TT_pp + 6480;         // SRC[j*80+i] = src[i][j]
  float* DL    = SRC + 6400;           // DL[i*80+a]  = d[i][a]
  float* MM0   = DL + 6400;            // MM partial, b in [0,40)
  float* MM1   = MM0 + 6720;           // MM partial, b in [40,80)
  float* FR    = MM1 + 6720;
  float* FA    = FR + 80;
  float* RD    = FA + 80;
  float* AD    = RD + 80;
  float* WSUM  = AD + 80;              // 2 x 16 (double-buffered norm partials)
  float* LSUM  = WSUM + 32;            // loss partials (16 waves)

  const int t = threadIdx.x;

  // ---- row sums + diagonals ----
  if (t < 80) {
    float s = 0.f;
    for (int b = 0; b < NN; ++b) s += recon[t * NN + b];
    FR[t] = s;
    RD[t] = recon[t * NN + t];
  } else if (t < 160) {
    const int i = t - 80;
    float s = 0.f;
    for (int j = 0; j < NN; ++j) s += adj[i * NN + j];
    FA[i] = s;
    AD[i] = adj[i * NN + i];
  }
  if (t < 32) WSUM[t] = (t == 0) ? 1.0f : 0.f;  // ||x0||^2 = 1
  __syncthreads();

  // ---- fill operand arrays + BCE loss over triu ----
  float lacc = 0.f;
  for (int f = t; f < NN * NN; f += NTHREADS) {
    const int r = f / NN, c = f % NN;
    XT_pp[PIDX(r, c)] = 1.0f / NN;  // x[i=r][a=c]
    TT_pp[PIDX(r, c)] = (r == c) ? 0.f : recon[r * NN + c] * RD[r] * RD[c];
    SRC[f] = (r == c) ? 0.f : adj[c * NN + r] * AD[c] * AD[r];
    DL[f] = AD[r] * RD[c] / (fabsf(FA[r] - FR[c]) + 1.f);
    if (c >= r) {
      const float tv = adj[f], p = recon[f];
      lacc -= tv * logf(p) + (1.f - tv) * logf(1.f - p);
    }
  }
  #pragma unroll
  for (int off = 32; off > 0; off >>= 1) lacc += __shfl_down(lacc, off, 64);
  if ((t & 63) == 0) LSUM[t >> 6] = lacc;
  __syncthreads();
  if (t == 0) {
    float s = 0.f;
    for (int w = 0; w < NTHREADS / 64; ++w) s += LSUM[w];
    out[0] = s / 3240.f;  // 80*81/2
  }

  // ---- thread mappings ----
  const bool actA = (t < 800);
  const int gA = t >= 400 ? 1 : 0;          // b-half (only meaningful t<800)
  const int uA = t - gA * 400;
  const int rtA = uA / 20, ctA = uA % 20;
  const int r0A = rtA * 4, c0A = ctA * 4;
  float* MMg = gA ? MM1 : MM0;

  const bool actB = (t < 800);
  const int rtB = t / 20;                   // 0..39 (2-row tiles)
  const int ctB = t - rtB * 20;             // 0..19 (4-col tiles)
  const int r0B = rtB * 2, c0B = ctB * 4;

  for (int it = 0; it < MITERS; ++it) {
    // Phase A: MM_g[j,a] = max_{b in half} x[j,b]*tgt[a,b]
    if (actA) {
      const float* xp = XT_pp + rtA * 324 + gA * 160;
      const float* tp = TT_pp + ctA * 324 + gA * 160;
      float m[4][4] = {{0.f, 0.f, 0.f, 0.f}, {0.f, 0.f, 0.f, 0.f},
                       {0.f, 0.f, 0.f, 0.f}, {0.f, 0.f, 0.f, 0.f}};
      #pragma unroll 2
      for (int b2 = 0; b2 < 20; ++b2) {
        const float4 xA = *(const float4*)(xp);
        const float4 xB = *(const float4*)(xp + 4);
        const float4 tA = *(const float4*)(tp);
        const float4 tB = *(const float4*)(tp + 4);
        xp += 8; tp += 8;
        const f32x2 xr[4] = {{xA.x, xA.y}, {xA.z, xA.w},
                             {xB.x, xB.y}, {xB.z, xB.w}};
        const f32x2 tc[4] = {{tA.x, tA.y}, {tA.z, tA.w},
                             {tB.x, tB.y}, {tB.z, tB.w}};
        #pragma unroll
        for (int r = 0; r < 4; ++r)
          #pragma unroll
          for (int c = 0; c < 4; ++c) {
            const f32x2 p = xr[r] * tc[c];
            MAX3(m[r][c], p.x, p.y);
          }
      }
      #pragma unroll
      for (int r = 0; r < 4; ++r)
        *(float4*)(MMg + (r0A + r) * MMSTRIDE + c0A) =
            make_float4(m[r][0], m[r][1], m[r][2], m[r][3]);
    }
    __syncthreads();

    // Combine: MM0 = max(MM0, MM1)
    for (int f = t; f < 1680; f += NTHREADS) {
      const float4 a = ((const float4*)MM0)[f];
      const float4 b = ((const float4*)MM1)[f];
      ((float4*)MM0)[f] = make_float4(fmaxf(a.x, b.x), fmaxf(a.y, b.y),
                                      fmaxf(a.z, b.z), fmaxf(a.w, b.w));
    }
    __syncthreads();

    // Phase B: xn = inv * (x*d + SRC^T @ MM0); 2x4 tiles, 800 threads
    const float* WIN = WSUM + ((it & 1) << 4);
    float* WOUT = WSUM + (((it + 1) & 1) << 4);
    float tot = 0.f;
    #pragma unroll
    for (int w = 0; w < NTHREADS / 64; ++w) tot += WIN[w];
    const float inv = 1.0f / sqrtf(tot);

    float ss = 0.f;
    if (actB) {
      f32x2 acc00 = {0.f, 0.f}, acc01 = {0.f, 0.f};
      f32x2 acc10 = {0.f, 0.f}, acc11 = {0.f, 0.f};
      const float* sp = SRC + r0B;
      const float* mp = MM0 + c0B;
      #pragma unroll 4
      for (int j = 0; j < NN; ++j) {
        const f32x2 sv = *(const f32x2*)sp;
        const float4 mq = *(const float4*)mp;
        sp += NN; mp += MMSTRIDE;
        const f32x2 m0 = {mq.x, mq.y};
        const f32x2 m1 = {mq.z, mq.w};
        const f32x2 s0 = {sv.x, sv.x};
        const f32x2 s1 = {sv.y, sv.y};
        acc00 = __builtin_elementwise_fma(s0, m0, acc00);
        acc01 = __builtin_elementwise_fma(s0, m1, acc01);
        acc10 = __builtin_elementwise_fma(s1, m0, acc10);
        acc11 = __builtin_elementwise_fma(s1, m1, acc11);
      }
      // epilogue: d-term, scale, ss, write back own 2x4 tile of XT
      float* xbA = XT_pp + (r0B >> 2) * 324 + (ctB * 2) * 8 + (r0B & 3) * 2;
      float* xbB = xbA + 8;
      const float4 qA = *(const float4*)xbA;  // {x(r0,c0),x(r0,c0+1),x(r1,c0),x(r1,c0+1)}
      const float4 qB = *(const float4*)xbB;  // cols c0+2,c0+3
      const float4 d0 = *(const float4*)(DL + r0B * NN + c0B);
      const float4 d1 = *(const float4*)(DL + (r0B + 1) * NN + c0B);
      const f32x2 iv = {inv, inv};
      f32x2 ssv = {0.f, 0.f};

      f32x2 xn00 = __builtin_elementwise_fma((f32x2){qA.x, qA.y},
                                             (f32x2){d0.x, d0.y}, acc00) * iv;
      f32x2 xn01 = __builtin_elementwise_fma((f32x2){qB.x, qB.y},
                                             (f32x2){d0.z, d0.w}, acc01) * iv;
      f32x2 xn10 = __builtin_elementwise_fma((f32x2){qA.z, qA.w},
                                             (f32x2){d1.x, d1.y}, acc10) * iv;
      f32x2 xn11 = __builtin_elementwise_fma((f32x2){qB.z, qB.w},
                                             (f32x2){d1.z, d1.w}, acc11) * iv;
      ssv = __builtin_elementwise_fma(xn00, xn00, ssv);
      ssv = __builtin_elementwise_fma(xn01, xn01, ssv);
      ssv = __builtin_elementwise_fma(xn10, xn10, ssv);
      ssv = __builtin_elementwise_fma(xn11, xn11, ssv);
      ss = ssv.x + ssv.y;
      *(float4*)xbA = make_float4(xn00.x, xn00.y, xn10.x, xn10.y);
      *(float4*)xbB = make_float4(xn01.x, xn01.y, xn11.x, xn11.y);
    }
    #pragma unroll
    for (int off = 32; off > 0; off >>= 1) ss += __shfl_down(ss, off, 64);
    if ((t & 63) == 0) WOUT[t >> 6] = ss;
    __syncthreads();
  }

  // ---- exact final normalization + un-transposed output ----
  float tot = 0.f;
  #pragma unroll
  for (int w = 0; w < NTHREADS / 64; ++w) tot += WSUM[((MITERS & 1) << 4) + w];
  const float finv = 1.0f / sqrtf(tot);
  for (int f = t; f < NN * NN; f += NTHREADS) {
    out[1 + f] = XT_pp[PIDX(f / NN, f % NN)] * finv;
  }
}

extern "C" void kernel_launch(void* const* d_in, const int* in_sizes, int n_in,
                              void* d_out, int out_size, void* d_ws, size_t ws_size,
                              hipStream_t stream) {
  const float* recon = (const float*)d_in[0];
  const float* adj   = (const float*)d_in[1];
  float* out = (float*)d_out;
  (void)in_sizes; (void)n_in; (void)out_size; (void)d_ws; (void)ws_size;

  const size_t lds_bytes = LDS_FLOATS * sizeof(float);  // 154.6 KiB (<160 KiB/CU)
  hipFuncSetAttribute(reinterpret_cast<const void*>(grf_kernel),
                      hipFuncAttributeMaxDynamicSharedMemorySize,
                      (int)lds_bytes);
  grf_kernel<<<1, NTHREADS, lds_bytes, stream>>>(recon, adj, out);
}

// Round 4
// 364.395 us; speedup vs baseline: 1.6011x; 1.6011x over previous
//
#include <hip/hip_runtime.h>
#include <math.h>

#define NN 80
#define MITERS 50
#define NTHREADS 1024

typedef _Float16 h8 __attribute__((ext_vector_type(8)));
typedef float f4 __attribute__((ext_vector_type(4)));

__device__ __forceinline__ unsigned pk_mul_f16(unsigned a, unsigned b) {
  unsigned d; asm("v_pk_mul_f16 %0, %1, %2" : "=v"(d) : "v"(a), "v"(b)); return d;
}
__device__ __forceinline__ unsigned pk_max_f16(unsigned a, unsigned b) {
  unsigned d; asm("v_pk_max_f16 %0, %1, %2" : "=v"(d) : "v"(a), "v"(b)); return d;
}
__device__ __forceinline__ h8 as_h8(uint4 u) {
  union { uint4 u; h8 h; } x; x.u = u; return x.h;
}

// ---- LDS byte offsets (all 16B-aligned) ----
// XH/TT: paired fp16 layout, 20 row-quads * 328 halfs (656 B) each
// MM0/MM1: fp16 [80][104] partial max buffers (j padded 80..96 zero)
// SRCH: fp16 [80][104] (0/1 values, pad zero)   DLT: f32 [80][84] (d transposed)
#define OFF_XH    0
#define OFF_TT    13120
#define OFF_MM0   26240
#define OFF_MM1   42880
#define OFF_SRCH  59520
#define OFF_DLT   76160
#define OFF_FR    103040
#define OFF_FA    103360
#define OFF_RD    103680
#define OFF_AD    104000
#define OFF_WSUM  104320   // 2 x 16 f32, double-buffered norm partials
#define OFF_LSUM  104448   // 16 f32 loss partials
#define LDS_BYTES 104512   // 102.1 KiB < 160 KiB

// paired fp16 byte index for element [r][k] of an 80x80 matrix
#define PB(r, k) ((((r) >> 2) * 656) + (((k) >> 1) * 16) + (((r) & 3) * 4) + (((k) & 1) * 2))

// one MFMA C-tile of phase B: C[i0..i0+16][a0..a0+16] = SRC @ max(MM0,MM1)
#define DO_TILE(I0, A0, AF)                                                   \
  {                                                                           \
    f4 acc = {0.f, 0.f, 0.f, 0.f};                                            \
    _Pragma("unroll")                                                         \
    for (int ks = 0; ks < 3; ++ks) {                                          \
      const int mo = ((A0) + la) * 208 + ks * 64 + gr * 16;                   \
      const uint4 b0 = *(const uint4*)(MM0b + mo);                            \
      const uint4 b1 = *(const uint4*)(MM1b + mo);                            \
      uint4 bb;                                                               \
      bb.x = pk_max_f16(b0.x, b1.x); bb.y = pk_max_f16(b0.y, b1.y);           \
      bb.z = pk_max_f16(b0.z, b1.z); bb.w = pk_max_f16(b0.w, b1.w);           \
      acc = __builtin_amdgcn_mfma_f32_16x16x32_f16(as_h8(AF[ks]),             \
                                                   as_h8(bb), acc, 0, 0, 0);  \
    }                                                                         \
    const int col = (A0) + la;                                                \
    const int rb = (I0) + gr * 4;                                             \
    const float4 dl = *(const float4*)(DLTb + col * 336 + rb * 4);            \
    char* xa = XHb + (rb >> 2) * 656 + (col >> 1) * 16 + (col & 1) * 2;       \
    const float xo0 = (float)*(const _Float16*)(xa);                          \
    const float xo1 = (float)*(const _Float16*)(xa + 4);                      \
    const float xo2 = (float)*(const _Float16*)(xa + 8);                      \
    const float xo3 = (float)*(const _Float16*)(xa + 12);                     \
    const float n0 = fmaf(xo0, dl.x, acc[0]) * inv;                           \
    const float n1 = fmaf(xo1, dl.y, acc[1]) * inv;                           \
    const float n2 = fmaf(xo2, dl.z, acc[2]) * inv;                           \
    const float n3 = fmaf(xo3, dl.w, acc[3]) * inv;                           \
    ss += n0 * n0 + n1 * n1 + n2 * n2 + n3 * n3;                              \
    *(_Float16*)(xa) = (_Float16)n0;                                          \
    *(_Float16*)(xa + 4) = (_Float16)n1;                                      \
    *(_Float16*)(xa + 8) = (_Float16)n2;                                      \
    *(_Float16*)(xa + 12) = (_Float16)n3;                                     \
  }

__global__ void __launch_bounds__(NTHREADS)
grf_kernel(const float* __restrict__ recon, const float* __restrict__ adj,
           float* __restrict__ out) {
  extern __shared__ char ldsb[];
  char* XHb = ldsb + OFF_XH;
  char* TTb = ldsb + OFF_TT;
  char* MM0b = ldsb + OFF_MM0;
  char* MM1b = ldsb + OFF_MM1;
  char* SRCHb = ldsb + OFF_SRCH;
  char* DLTb = ldsb + OFF_DLT;
  float* FR = (float*)(ldsb + OFF_FR);
  float* FA = (float*)(ldsb + OFF_FA);
  float* RD = (float*)(ldsb + OFF_RD);
  float* AD = (float*)(ldsb + OFF_AD);
  float* WSUM = (float*)(ldsb + OFF_WSUM);
  float* LSUM = (float*)(ldsb + OFF_LSUM);

  const int t = threadIdx.x;
  const int wave = t >> 6, lane = t & 63;
  const int la = lane & 15, gr = lane >> 4;

  // ---- row sums + diagonals ----
  if (t < 80) {
    float s = 0.f;
    for (int b = 0; b < NN; ++b) s += recon[t * NN + b];
    FR[t] = s;
    RD[t] = recon[t * NN + t];
  } else if (t < 160) {
    const int i = t - 80;
    float s = 0.f;
    for (int j = 0; j < NN; ++j) s += adj[i * NN + j];
    FA[i] = s;
    AD[i] = adj[i * NN + i];
  }
  if (t < 32) {
    const float q = (float)(_Float16)(1.0f / 80.0f);
    WSUM[t] = (t == 0) ? 6400.0f * q * q : 0.f;  // ||quantized x0||^2
  }
  __syncthreads();

  // ---- fill operand arrays + BCE loss over triu ----
  float lacc = 0.f;
  for (int f = t; f < NN * NN; f += NTHREADS) {
    const int r = f / NN, c = f - (f / NN) * NN;
    *(_Float16*)(XHb + PB(r, c)) = (_Float16)(1.0f / 80.0f);        // y0[i=r][a=c]
    const float tv = (r == c) ? 0.f : recon[r * NN + c] * RD[r] * RD[c];
    *(_Float16*)(TTb + PB(r, c)) = (_Float16)tv;                    // tgt[a=r][b=c]
    *(float*)(DLTb + (c * 84 + r) * 4) =
        AD[r] * RD[c] / (fabsf(FA[r] - FR[c]) + 1.f);               // DLT[a=c][i=r]
    const float sv = (r == c) ? 0.f : adj[r * NN + c] * AD[r] * AD[c];
    *(_Float16*)(SRCHb + (r * 104 + c) * 2) = (_Float16)sv;         // SRCH[i=r][j=c]
    if (c >= r) {
      const float tb = adj[f], p = recon[f];
      lacc -= tb * logf(p) + (1.f - tb) * logf(1.f - p);
    }
  }
  // zero pads: SRCH j in [80,104) and all of MM0/MM1 (contiguous, 8320 u32)
  for (int f = t; f < 1920; f += NTHREADS) {
    const int r = f / 24, j = 80 + (f - (f / 24) * 24);
    *(_Float16*)(SRCHb + (r * 104 + j) * 2) = (_Float16)0.f;
  }
  for (int f = t; f < 8320; f += NTHREADS) *(unsigned*)(MM0b + f * 4) = 0u;

  #pragma unroll
  for (int off = 32; off > 0; off >>= 1) lacc += __shfl_down(lacc, off, 64);
  if (lane == 0) LSUM[wave] = lacc;
  __syncthreads();
  if (t == 0) {
    float s = 0.f;
    for (int w = 0; w < 16; ++w) s += LSUM[w];
    out[0] = s / 3240.f;  // 80*81/2
  }

  // ---- per-wave persistent SRC A-fragments (registers, all 50 iters) ----
  const int i00 = (wave / 5) * 16, a00 = (wave % 5) * 16;       // tile tt = wave
  const int tt1 = wave + 16;
  const bool has2 = tt1 < 25;
  const int i01 = has2 ? (tt1 / 5) * 16 : 0;
  const int a01 = has2 ? (tt1 % 5) * 16 : 0;
  uint4 af0[3], af1[3];
  af1[0] = af1[1] = af1[2] = make_uint4(0u, 0u, 0u, 0u);
  #pragma unroll
  for (int ks = 0; ks < 3; ++ks)
    af0[ks] = *(const uint4*)(SRCHb + (i00 + la) * 208 + ks * 64 + gr * 16);
  if (has2) {
    #pragma unroll
    for (int ks = 0; ks < 3; ++ks)
      af1[ks] = *(const uint4*)(SRCHb + (i01 + la) * 208 + ks * 64 + gr * 16);
  }

  // ---- phase-A thread mapping (800 threads, 2-way b-split) ----
  const bool actA = t < 800;
  const int g = (t >= 400) ? 1 : 0;
  const int u = g ? t - 400 : t;
  const int rtA = u / 20, ctA = u - (u / 20) * 20;
  const char* xAp = XHb + rtA * 656 + g * 320;
  const char* tAp = TTb + ctA * 656 + g * 320;
  char* mwp = (g ? MM1b : MM0b) + ctA * 4 * 208 + rtA * 8;

  for (int it = 0; it < MITERS; ++it) {
    // ---- Phase A: MMg[j,a] = max over half-b of y[j,b]*tgt[a,b] (pk fp16) ----
    if (actA) {
      unsigned m[4][4] = {{0u, 0u, 0u, 0u}, {0u, 0u, 0u, 0u},
                          {0u, 0u, 0u, 0u}, {0u, 0u, 0u, 0u}};
      #pragma unroll 4
      for (int cc = 0; cc < 20; ++cc) {
        const uint4 xq = *(const uint4*)(xAp + cc * 16);
        const uint4 tq = *(const uint4*)(tAp + cc * 16);
        const unsigned xr[4] = {xq.x, xq.y, xq.z, xq.w};
        const unsigned tc[4] = {tq.x, tq.y, tq.z, tq.w};
        #pragma unroll
        for (int r = 0; r < 4; ++r)
          #pragma unroll
          for (int c = 0; c < 4; ++c)
            m[r][c] = pk_max_f16(m[r][c], pk_mul_f16(xr[r], tc[c]));
      }
      #pragma unroll
      for (int c = 0; c < 4; ++c) {
        unsigned fr[4];
        #pragma unroll
        for (int r = 0; r < 4; ++r) {
          const unsigned v = m[r][c];
          fr[r] = pk_max_f16(v, (v >> 16) | (v << 16));  // fold b-pair max
        }
        const unsigned w0 = (fr[0] & 0xffffu) | (fr[1] << 16);
        const unsigned w1 = (fr[2] & 0xffffu) | (fr[3] << 16);
        *(uint2*)(mwp + c * 208) = make_uint2(w0, w1);
      }
    }
    __syncthreads();

    // ---- Phase B: y_new = inv * (y*d + SRC @ max(MM0,MM1)) via MFMA ----
    const float* WIN = WSUM + ((it & 1) << 4);
    const float4 wa = *(const float4*)(WIN);
    const float4 wb = *(const float4*)(WIN + 4);
    const float4 wc = *(const float4*)(WIN + 8);
    const float4 wd = *(const float4*)(WIN + 12);
    const float tot = ((wa.x + wa.y) + (wa.z + wa.w)) +
                      ((wb.x + wb.y) + (wb.z + wb.w)) +
                      ((wc.x + wc.y) + (wc.z + wc.w)) +
                      ((wd.x + wd.y) + (wd.z + wd.w));
    const float inv = 1.0f / sqrtf(tot);

    float ss = 0.f;
    DO_TILE(i00, a00, af0);
    if (has2) DO_TILE(i01, a01, af1);

    #pragma unroll
    for (int off = 32; off > 0; off >>= 1) ss += __shfl_down(ss, off, 64);
    if (lane == 0) WSUM[(((it + 1) & 1) << 4) + wave] = ss;
    __syncthreads();
  }

  // ---- exact final normalization + output (out[1 + i*80 + a]) ----
  {
    const float* WF = WSUM + ((MITERS & 1) << 4);
    float tot = 0.f;
    #pragma unroll
    for (int w = 0; w < 16; ++w) tot += WF[w];
    const float finv = 1.0f / sqrtf(tot);
    for (int f = t; f < NN * NN; f += NTHREADS) {
      const int i = f / NN, a = f - (f / NN) * NN;
      out[1 + f] = (float)*(const _Float16*)(XHb + PB(i, a)) * finv;
    }
  }
}

extern "C" void kernel_launch(void* const* d_in, const int* in_sizes, int n_in,
                              void* d_out, int out_size, void* d_ws, size_t ws_size,
                              hipStream_t stream) {
  const float* recon = (const float*)d_in[0];
  const float* adj   = (const float*)d_in[1];
  float* out = (float*)d_out;
  (void)in_sizes; (void)n_in; (void)out_size; (void)d_ws; (void)ws_size;

  hipFuncSetAttribute(reinterpret_cast<const void*>(grf_kernel),
                      hipFuncAttributeMaxDynamicSharedMemorySize, LDS_BYTES);
  grf_kernel<<<1, NTHREADS, LDS_BYTES, stream>>>(recon, adj, out);
}